// Round 1
// baseline (618.931 us; speedup 1.0000x reference)
//
#include <hip/hip_runtime.h>
#include <stdint.h>

// Problem constants (reference: N=8192, IN_DIM=512, LDIM=256)
#define NN 8192
#define KDIM 512
#define LDIM 256

typedef short bf16x8 __attribute__((ext_vector_type(8)));
typedef float f32x4 __attribute__((ext_vector_type(4)));

// fp32 -> bf16 with round-to-nearest-even
__device__ __forceinline__ unsigned short f2bf(float f) {
  unsigned int u = __float_as_uint(f);
  u = (u + 0x7fffu + ((u >> 16) & 1u)) >> 16;
  return (unsigned short)u;
}

// async global->LDS, 16B per lane; LDS dest = wave-uniform base + lane*16
__device__ __forceinline__ void async_ld16(const unsigned short* g, unsigned short* l) {
  __builtin_amdgcn_global_load_lds(
      (const __attribute__((address_space(1))) unsigned int*)g,
      (__attribute__((address_space(3))) unsigned int*)l, 16, 0, 0);
}

// Cast x [8192x512] and proj_w [256x512] to bf16. Grid exactly covers x.
__global__ __launch_bounds__(256) void cast_kernel(
    const float* __restrict__ x, const float* __restrict__ pw,
    unsigned short* __restrict__ xb, unsigned short* __restrict__ pwb) {
  int i = blockIdx.x * 256 + threadIdx.x;
  xb[i] = f2bf(x[i]);
  if (i < LDIM * KDIM) pwb[i] = f2bf(pw[i]);
}

// Row-normalize x_hat, emit A = bf16(xn*w), B = bf16(xn). One block per row.
__global__ __launch_bounds__(256) void norm_kernel(
    const float* __restrict__ xh, const float* __restrict__ w,
    unsigned short* __restrict__ Ab, unsigned short* __restrict__ Bb) {
  const int row = blockIdx.x;
  const int d = threadIdx.x;
  const float v = xh[row * LDIM + d];
  float ss = v * v;
#pragma unroll
  for (int m = 1; m < 64; m <<= 1) ss += __shfl_xor(ss, m);
  __shared__ float s4[4];
  if ((d & 63) == 0) s4[d >> 6] = ss;
  __syncthreads();
  const float tot = s4[0] + s4[1] + s4[2] + s4[3];
  const float inv = 1.0f / sqrtf(tot);
  const float xn = v * inv;
  Bb[row * LDIM + d] = f2bf(xn);
  Ab[row * LDIM + d] = f2bf(xn * w[d]);
}

// D = A * B^T, A [M,K] bf16 K-major, B [N,K] bf16 K-major.
// 128x128 tile, BK=32, 256 threads = 4 waves (2x2), each wave 64x64 via
// 4x4 grid of v_mfma_f32_16x16x32_bf16. m97-style global_load_lds staging.
// EPI=false: store D (fp32) to C (ldC cols).
// EPI=true : t = adj*exp(-D); store t to C; accumulate rowsum via
//            shuffle-reduce -> LDS -> 1 global atomic per row per block.
template <int K, bool EPI>
__global__ __launch_bounds__(256) void gemm_bt(
    const unsigned short* __restrict__ A,
    const unsigned short* __restrict__ B,
    float* __restrict__ C,
    const float* __restrict__ adj,
    float* __restrict__ rowsum,
    int ldC) {
  __shared__ unsigned short As[128 * 32];
  __shared__ unsigned short Bs[128 * 32];
  __shared__ float rs[128];

  const int tid = threadIdx.x;
  const int wave = tid >> 6;
  const int lane = tid & 63;
  const int quad = lane >> 4;
  const int l16 = lane & 15;
  const int wm = wave >> 1;
  const int wn = wave & 1;

  if (EPI && tid < 128) rs[tid] = 0.0f;

  const size_t row0 = (size_t)blockIdx.y * 128;
  const size_t col0 = (size_t)blockIdx.x * 128;

  // staging map: chunk c = wave*128 + s*64 + lane covers LDS bytes [c*16, c*16+16)
  // tile layout [128 rows][32 k] bf16 => row m = c>>2, k offset = (c&3)*8
  const int c0 = wave * 128 + lane;
  const int mA = c0 >> 2;
  const int kA = (c0 & 3) * 8;
  const unsigned short* Ag = A + (row0 + mA) * (size_t)K + kA;
  const unsigned short* Bg = B + (col0 + mA) * (size_t)K + kA;
  char* AsB = (char*)As;
  char* BsB = (char*)Bs;
  unsigned short* dA0 = (unsigned short*)(AsB + wave * 2048);
  unsigned short* dA1 = (unsigned short*)(AsB + wave * 2048 + 1024);
  unsigned short* dB0 = (unsigned short*)(BsB + wave * 2048);
  unsigned short* dB1 = (unsigned short*)(BsB + wave * 2048 + 1024);

  f32x4 acc[4][4];
#pragma unroll
  for (int i = 0; i < 4; ++i)
#pragma unroll
    for (int j = 0; j < 4; ++j) acc[i][j] = (f32x4)(0.0f);

  for (int k0 = 0; k0 < K; k0 += 32) {
    async_ld16(Ag + k0, dA0);
    async_ld16(Ag + 16 * (size_t)K + k0, dA1);  // row m+16, same k offset
    async_ld16(Bg + k0, dB0);
    async_ld16(Bg + 16 * (size_t)K + k0, dB1);
    __syncthreads();  // drains vmcnt: staging complete

    bf16x8 av[4], bv[4];
#pragma unroll
    for (int mt = 0; mt < 4; ++mt)
      av[mt] = *(const bf16x8*)(AsB + (wm * 64 + mt * 16 + l16) * 64 + quad * 16);
#pragma unroll
    for (int nt = 0; nt < 4; ++nt)
      bv[nt] = *(const bf16x8*)(BsB + (wn * 64 + nt * 16 + l16) * 64 + quad * 16);
#pragma unroll
    for (int mt = 0; mt < 4; ++mt)
#pragma unroll
      for (int nt = 0; nt < 4; ++nt)
        acc[mt][nt] = __builtin_amdgcn_mfma_f32_16x16x32_bf16(av[mt], bv[nt], acc[mt][nt], 0, 0, 0);
    __syncthreads();  // all waves done reading LDS before next stage
  }

  if (!EPI) {
#pragma unroll
    for (int mt = 0; mt < 4; ++mt)
#pragma unroll
      for (int nt = 0; nt < 4; ++nt)
#pragma unroll
        for (int r = 0; r < 4; ++r) {
          // C/D layout: col = lane&15, row = quad*4 + reg [m89/m91 verified]
          size_t gr = row0 + wm * 64 + mt * 16 + quad * 4 + r;
          size_t gc = col0 + wn * 64 + nt * 16 + l16;
          C[gr * (size_t)ldC + gc] = acc[mt][nt][r];
        }
  } else {
#pragma unroll
    for (int mt = 0; mt < 4; ++mt) {
      float rsum[4] = {0.f, 0.f, 0.f, 0.f};
#pragma unroll
      for (int nt = 0; nt < 4; ++nt) {
#pragma unroll
        for (int r = 0; r < 4; ++r) {
          size_t gr = row0 + wm * 64 + mt * 16 + quad * 4 + r;
          size_t gc = col0 + wn * 64 + nt * 16 + l16;
          size_t idx = gr * (size_t)ldC + gc;
          float t = adj[idx] * __expf(-acc[mt][nt][r]);
          C[idx] = t;
          rsum[r] += t;
        }
      }
      // reduce the 16 columns of each 16x16 tile row (lanes l16=0..15)
#pragma unroll
      for (int r = 0; r < 4; ++r) {
        float v = rsum[r];
        v += __shfl_xor(v, 1);
        v += __shfl_xor(v, 2);
        v += __shfl_xor(v, 4);
        v += __shfl_xor(v, 8);
        if (l16 == 0) atomicAdd(&rs[wm * 64 + mt * 16 + quad * 4 + r], v);
      }
    }
    __syncthreads();
    if (tid < 128) atomicAdd(&rowsum[row0 + tid], rs[tid]);
  }
}

// In-place: out = t / rowsum[row] + 1e-10, float4 vectorized (2048 float4/row)
__global__ __launch_bounds__(256) void scale_kernel(
    float* __restrict__ t, const float* __restrict__ rowsum) {
  const size_t i = (size_t)blockIdx.x * 256 + threadIdx.x;
  const int row = (int)(i >> 11);
  float4 v = ((float4*)t)[i];
  const float inv = 1.0f / rowsum[row];
  v.x = v.x * inv + 1e-10f;
  v.y = v.y * inv + 1e-10f;
  v.z = v.z * inv + 1e-10f;
  v.w = v.w * inv + 1e-10f;
  ((float4*)t)[i] = v;
}

extern "C" void kernel_launch(void* const* d_in, const int* in_sizes, int n_in,
                              void* d_out, int out_size, void* d_ws, size_t ws_size,
                              hipStream_t stream) {
  (void)in_sizes; (void)n_in; (void)out_size; (void)ws_size;
  const float* x   = (const float*)d_in[0];  // [8192,512]
  const float* adj = (const float*)d_in[1];  // [8192,8192]
  const float* pw  = (const float*)d_in[2];  // [256,512]
  const float* lw  = (const float*)d_in[3];  // [256]
  float* out = (float*)d_out;                // [8192,8192]
  char* ws = (char*)d_ws;

  // ws layout (bytes): ~24.3 MB total
  unsigned short* xb   = (unsigned short*)(ws);              // 8 MB
  unsigned short* pwb  = (unsigned short*)(ws + 8388608);    // 256 KB
  float*          xhat = (float*)(ws + 8650752);             // 8 MB
  unsigned short* Ab   = (unsigned short*)(ws + 17039360);   // 4 MB
  unsigned short* Bb   = (unsigned short*)(ws + 21233664);   // 4 MB
  float*          rsum = (float*)(ws + 25427968);            // 32 KB

  // 1) cast inputs to bf16
  cast_kernel<<<(NN * KDIM) / 256, 256, 0, stream>>>(x, pw, xb, pwb);
  // 2) x_hat = x @ proj_w^T : M=8192, N=256, K=512
  gemm_bt<KDIM, false><<<dim3(2, 64), 256, 0, stream>>>(xb, pwb, xhat, nullptr, nullptr, LDIM);
  // 3) normalize rows; A = xn*w, B = xn (bf16)
  norm_kernel<<<NN, 256, 0, stream>>>(xhat, lw, Ab, Bb);
  // 4) t = adj * exp(-(A@B^T)) into d_out, plus rowsums
  hipMemsetAsync(rsum, 0, NN * sizeof(float), stream);
  gemm_bt<LDIM, true><<<dim3(64, 64), 256, 0, stream>>>(Ab, Bb, out, adj, rsum, NN);
  // 5) out = t / rowsum + eps (in place)
  scale_kernel<<<(NN / 4) * (NN / 256), 256, 0, stream>>>(out, rsum);
}

// Round 2
// 542.286 us; speedup vs baseline: 1.1413x; 1.1413x over previous
//
#include <hip/hip_runtime.h>
#include <stdint.h>

// Problem constants (reference: N=8192, IN_DIM=512, LDIM=256)
#define NN 8192
#define KDIM 512
#define LDIM 256

typedef short bf16x8 __attribute__((ext_vector_type(8)));
typedef short short8 __attribute__((ext_vector_type(8)));
typedef float f32x4 __attribute__((ext_vector_type(4)));

// fp32 -> bf16 with round-to-nearest-even
__device__ __forceinline__ unsigned short f2bf(float f) {
  unsigned int u = __float_as_uint(f);
  u = (u + 0x7fffu + ((u >> 16) & 1u)) >> 16;
  return (unsigned short)u;
}
__device__ __forceinline__ float bf2f(unsigned short s) {
  return __uint_as_float(((unsigned int)s) << 16);
}

// async global->LDS, 16B per lane; LDS dest = wave-uniform base + lane*16
__device__ __forceinline__ void async_ld16(const unsigned short* g, unsigned short* l) {
  __builtin_amdgcn_global_load_lds(
      (const __attribute__((address_space(1))) unsigned int*)g,
      (__attribute__((address_space(3))) unsigned int*)l, 16, 0, 0);
}

// Cast x [8192x512] and proj_w [256x512] to bf16. Grid exactly covers x.
__global__ __launch_bounds__(256) void cast_kernel(
    const float* __restrict__ x, const float* __restrict__ pw,
    unsigned short* __restrict__ xb, unsigned short* __restrict__ pwb) {
  int i = blockIdx.x * 256 + threadIdx.x;
  xb[i] = f2bf(x[i]);
  if (i < LDIM * KDIM) pwb[i] = f2bf(pw[i]);
}

// Row-normalize x_hat, emit A = bf16(xn*w), B = bf16(xn). One block per row.
__global__ __launch_bounds__(256) void norm_kernel(
    const float* __restrict__ xh, const float* __restrict__ w,
    unsigned short* __restrict__ Ab, unsigned short* __restrict__ Bb) {
  const int row = blockIdx.x;
  const int d = threadIdx.x;
  const float v = xh[row * LDIM + d];
  float ss = v * v;
#pragma unroll
  for (int m = 1; m < 64; m <<= 1) ss += __shfl_xor(ss, m);
  __shared__ float s4[4];
  if ((d & 63) == 0) s4[d >> 6] = ss;
  __syncthreads();
  const float tot = s4[0] + s4[1] + s4[2] + s4[3];
  const float inv = 1.0f / sqrtf(tot);
  const float xn = v * inv;
  Bb[row * LDIM + d] = f2bf(xn);
  Ab[row * LDIM + d] = f2bf(xn * w[d]);
}

// D = A * B^T, A [M,K] bf16 K-major, B [N,K] bf16 K-major.
// 128x128 tile, BK=32, 256 threads = 4 waves (2x2), each wave 64x64 via
// 4x4 grid of v_mfma_f32_16x16x32_bf16. m97-style global_load_lds staging.
// MODE 0: store D (fp32) to C (ldC cols).                      [GEMM1]
// MODE 1: t = adj*exp(-D) -> bf16 to T; rowsum atomics.        [GEMM2, big ws]
// MODE 2: t = adj*exp(-D) -> fp32 to C; rowsum atomics.        [GEMM2, fallback]
// MODE 1/2 epilogue: LDS-transpose each 32x128 acc slab so every thread owns
// 16 contiguous columns of one row -> float4 adj loads, 16B stores.
template <int K, int MODE>
__global__ __launch_bounds__(256) void gemm_bt(
    const unsigned short* __restrict__ A,
    const unsigned short* __restrict__ B,
    float* __restrict__ C,
    unsigned short* __restrict__ T,
    const float* __restrict__ adj,
    float* __restrict__ rowsum,
    int ldC) {
  __shared__ unsigned short As[128 * 32];
  __shared__ unsigned short Bs[128 * 32];
  __shared__ float rs[128];

  const int tid = threadIdx.x;
  const int wave = tid >> 6;
  const int lane = tid & 63;
  const int quad = lane >> 4;
  const int l16 = lane & 15;
  const int wm = wave >> 1;
  const int wn = wave & 1;

  const size_t row0 = (size_t)blockIdx.y * 128;
  const size_t col0 = (size_t)blockIdx.x * 128;

  // staging map: chunk c = wave*128 + lane covers LDS bytes [c*16, c*16+16)
  // tile layout [128 rows][32 k] bf16 => row m = c>>2, k offset = (c&3)*8
  const int c0 = wave * 128 + lane;
  const int mA = c0 >> 2;
  const int kA = (c0 & 3) * 8;
  const unsigned short* Ag = A + (row0 + mA) * (size_t)K + kA;
  const unsigned short* Bg = B + (col0 + mA) * (size_t)K + kA;
  char* AsB = (char*)As;
  char* BsB = (char*)Bs;
  unsigned short* dA0 = (unsigned short*)(AsB + wave * 2048);
  unsigned short* dA1 = (unsigned short*)(AsB + wave * 2048 + 1024);
  unsigned short* dB0 = (unsigned short*)(BsB + wave * 2048);
  unsigned short* dB1 = (unsigned short*)(BsB + wave * 2048 + 1024);

  f32x4 acc[4][4];
#pragma unroll
  for (int i = 0; i < 4; ++i)
#pragma unroll
    for (int j = 0; j < 4; ++j) acc[i][j] = (f32x4)(0.0f);

  for (int k0 = 0; k0 < K; k0 += 32) {
    async_ld16(Ag + k0, dA0);
    async_ld16(Ag + 16 * (size_t)K + k0, dA1);  // row m+16, same k offset
    async_ld16(Bg + k0, dB0);
    async_ld16(Bg + 16 * (size_t)K + k0, dB1);
    __syncthreads();  // drains vmcnt: staging complete

    bf16x8 av[4], bv[4];
#pragma unroll
    for (int mt = 0; mt < 4; ++mt)
      av[mt] = *(const bf16x8*)(AsB + (wm * 64 + mt * 16 + l16) * 64 + quad * 16);
#pragma unroll
    for (int nt = 0; nt < 4; ++nt)
      bv[nt] = *(const bf16x8*)(BsB + (wn * 64 + nt * 16 + l16) * 64 + quad * 16);
#pragma unroll
    for (int mt = 0; mt < 4; ++mt)
#pragma unroll
      for (int nt = 0; nt < 4; ++nt)
        acc[mt][nt] = __builtin_amdgcn_mfma_f32_16x16x32_bf16(av[mt], bv[nt], acc[mt][nt], 0, 0, 0);
    __syncthreads();  // all waves done reading LDS before next stage
  }

  if constexpr (MODE == 0) {
#pragma unroll
    for (int mt = 0; mt < 4; ++mt)
#pragma unroll
      for (int nt = 0; nt < 4; ++nt)
#pragma unroll
        for (int r = 0; r < 4; ++r) {
          // C/D layout: col = lane&15, row = quad*4 + reg [m89/m91 verified]
          size_t gr = row0 + wm * 64 + mt * 16 + quad * 4 + r;
          size_t gc = col0 + wn * 64 + nt * 16 + l16;
          C[gr * (size_t)ldC + gc] = acc[mt][nt][r];
        }
  } else {
    // 32x128 slab transpose; stride 132 keeps write conflicts 2-way (free)
    __shared__ float trans[32 * 132];
    const int s = tid >> 3;   // 0..31: slab-local row this thread consumes
    const int cb = tid & 7;   // 8 threads/row, 16 cols each
    const int coff = cb * 16;
#pragma unroll
    for (int mt = 0; mt < 4; ++mt) {
      __syncthreads();  // prior slab's reads done before overwrite
#pragma unroll
      for (int nt = 0; nt < 4; ++nt)
#pragma unroll
        for (int r = 0; r < 4; ++r)
          trans[(wm * 16 + quad * 4 + r) * 132 + wn * 64 + nt * 16 + l16] =
              acc[mt][nt][r];
      __syncthreads();
      // slab row s -> global row
      const size_t gr = row0 + (size_t)(s >> 4) * 64 + mt * 16 + (s & 15);
      const float* arow = adj + gr * NN + col0 + coff;
      float av16[16];
#pragma unroll
      for (int q = 0; q < 4; ++q) {
        float4 a4 = ((const float4*)arow)[q];
        av16[q * 4 + 0] = a4.x;
        av16[q * 4 + 1] = a4.y;
        av16[q * 4 + 2] = a4.z;
        av16[q * 4 + 3] = a4.w;
      }
      const float* drow = &trans[s * 132 + coff];
      float part = 0.0f;
      if constexpr (MODE == 1) {
        short8 p0, p1;
#pragma unroll
        for (int j = 0; j < 16; ++j) {
          float tv = av16[j] * __expf(-drow[j]);
          unsigned short us = f2bf(tv);
          part += bf2f(us);  // rowsum of the *rounded* t: self-consistent
          if (j < 8) p0[j] = (short)us; else p1[j - 8] = (short)us;
        }
        short8* trow = (short8*)(T + gr * NN + col0 + coff);
        trow[0] = p0;
        trow[1] = p1;
      } else {
        float4 o[4];
#pragma unroll
        for (int j = 0; j < 16; ++j) {
          float tv = av16[j] * __expf(-drow[j]);
          part += tv;
          ((float*)o)[j] = tv;
        }
        float4* crow = (float4*)(C + gr * NN + col0 + coff);
#pragma unroll
        for (int q = 0; q < 4; ++q) crow[q] = o[q];
      }
      // reduce the 8 threads sharing this row (lanes s*8..s*8+7)
      part += __shfl_xor(part, 1);
      part += __shfl_xor(part, 2);
      part += __shfl_xor(part, 4);
      if (cb == 0) rs[(s >> 4) * 64 + mt * 16 + (s & 15)] = part;  // unique owner
    }
    __syncthreads();
    if (tid < 128) atomicAdd(&rowsum[row0 + tid], rs[tid]);
  }
}

// out = bf16(t) * (1/rowsum[row]) + 1e-10; read ushort8, write 2x float4
__global__ __launch_bounds__(256) void scale_bf16_kernel(
    const unsigned short* __restrict__ T, const float* __restrict__ rowsum,
    float* __restrict__ out) {
  const size_t i = (size_t)blockIdx.x * 256 + threadIdx.x;  // short8 index
  const int row = (int)(i >> 10);  // 1024 short8 per row
  short8 tv = ((const short8*)T)[i];
  const float inv = 1.0f / rowsum[row];
  float4 o0, o1;
  o0.x = bf2f((unsigned short)tv[0]) * inv + 1e-10f;
  o0.y = bf2f((unsigned short)tv[1]) * inv + 1e-10f;
  o0.z = bf2f((unsigned short)tv[2]) * inv + 1e-10f;
  o0.w = bf2f((unsigned short)tv[3]) * inv + 1e-10f;
  o1.x = bf2f((unsigned short)tv[4]) * inv + 1e-10f;
  o1.y = bf2f((unsigned short)tv[5]) * inv + 1e-10f;
  o1.z = bf2f((unsigned short)tv[6]) * inv + 1e-10f;
  o1.w = bf2f((unsigned short)tv[7]) * inv + 1e-10f;
  ((float4*)out)[i * 2] = o0;
  ((float4*)out)[i * 2 + 1] = o1;
}

// Fallback: in-place out = t / rowsum[row] + 1e-10 (t fp32 already in out)
__global__ __launch_bounds__(256) void scale_f32_kernel(
    float* __restrict__ t, const float* __restrict__ rowsum) {
  const size_t i = (size_t)blockIdx.x * 256 + threadIdx.x;
  const int row = (int)(i >> 11);
  float4 v = ((float4*)t)[i];
  const float inv = 1.0f / rowsum[row];
  v.x = v.x * inv + 1e-10f;
  v.y = v.y * inv + 1e-10f;
  v.z = v.z * inv + 1e-10f;
  v.w = v.w * inv + 1e-10f;
  ((float4*)t)[i] = v;
}

extern "C" void kernel_launch(void* const* d_in, const int* in_sizes, int n_in,
                              void* d_out, int out_size, void* d_ws, size_t ws_size,
                              hipStream_t stream) {
  (void)in_sizes; (void)n_in; (void)out_size;
  const float* x   = (const float*)d_in[0];  // [8192,512]
  const float* adj = (const float*)d_in[1];  // [8192,8192]
  const float* pw  = (const float*)d_in[2];  // [256,512]
  const float* lw  = (const float*)d_in[3];  // [256]
  float* out = (float*)d_out;                // [8192,8192]
  char* ws = (char*)d_ws;

  // ws layout (bytes)
  unsigned short* xb   = (unsigned short*)(ws);              // 8 MB
  unsigned short* pwb  = (unsigned short*)(ws + 8388608);    // 256 KB
  float*          xhat = (float*)(ws + 8650752);             // 8 MB
  unsigned short* Ab   = (unsigned short*)(ws + 17039360);   // 4 MB
  unsigned short* Bb   = (unsigned short*)(ws + 21233664);   // 4 MB
  float*          rsum = (float*)(ws + 25427968);            // 32 KB
  unsigned short* Tbuf = (unsigned short*)(ws + 25460736);   // 128 MB (if fits)
  const bool big_ws = ws_size >= 25460736ull + (size_t)NN * NN * 2ull;

  // 1) cast inputs to bf16
  cast_kernel<<<(NN * KDIM) / 256, 256, 0, stream>>>(x, pw, xb, pwb);
  // 2) x_hat = x @ proj_w^T : M=8192, N=256, K=512
  gemm_bt<KDIM, 0><<<dim3(2, 64), 256, 0, stream>>>(xb, pwb, xhat, nullptr, nullptr, nullptr, LDIM);
  // 3) normalize rows; A = xn*w, B = xn (bf16)
  norm_kernel<<<NN, 256, 0, stream>>>(xhat, lw, Ab, Bb);
  // 4) t = adj * exp(-(A@B^T)), plus rowsums
  hipMemsetAsync(rsum, 0, NN * sizeof(float), stream);
  if (big_ws) {
    gemm_bt<LDIM, 1><<<dim3(64, 64), 256, 0, stream>>>(Ab, Bb, nullptr, Tbuf, adj, rsum, NN);
    // 5) out = t / rowsum + eps
    scale_bf16_kernel<<<(NN / 8) * (NN / 256), 256, 0, stream>>>(Tbuf, rsum, out);
  } else {
    gemm_bt<LDIM, 2><<<dim3(64, 64), 256, 0, stream>>>(Ab, Bb, out, nullptr, adj, rsum, NN);
    scale_f32_kernel<<<(NN / 4) * (NN / 256), 256, 0, stream>>>(out, rsum);
  }
}